// Round 15
// baseline (388.461 us; speedup 1.0000x reference)
//
#include <hip/hip_runtime.h>
#include <hip/hip_bf16.h>

// Problem constants (B=4, S=2048, D=1024, E=8, F=4096)
#define TOKENS   8192
#define DDIM     1024
#define NEXP     8
#define FDIM     4096
#define CAPACITY 1280
#define NYT      10         // CAPACITY / 128 M-tiles

typedef __attribute__((ext_vector_type(8))) __bf16 bf16x8;
typedef __attribute__((ext_vector_type(4))) __bf16 bf16x4;
typedef __attribute__((ext_vector_type(4))) float  f32x4;

typedef __attribute__((address_space(1))) const void gvoid_t;
typedef __attribute__((address_space(3))) void       lvoid_t;

__device__ __forceinline__ void async16(const void* g, void* l) {
  // 16B per lane; LDS dest = wave-uniform base + lane*16 (HW behavior)
  __builtin_amdgcn_global_load_lds((gvoid_t*)g, (lvoid_t*)l, 16, 0, 0);
}

// ---------------- gating: logits, softmax, top-1 (all f32, must match ref routing) --------
__global__ void gate_kernel(const float* __restrict__ x, const float* __restrict__ gw,
                            int* __restrict__ eidx, float* __restrict__ prob) {
  const int t = blockIdx.x;
  const int lane = threadIdx.x;           // 64 threads
  const float* xp = x + (size_t)t * DDIM;
  float acc[NEXP];
#pragma unroll
  for (int e = 0; e < NEXP; ++e) acc[e] = 0.f;
#pragma unroll 4
  for (int i = 0; i < DDIM / 64; ++i) {
    const int d = i * 64 + lane;
    const float xv = xp[d];
    const f32x4 g0 = *(const f32x4*)(gw + d * NEXP);
    const f32x4 g1 = *(const f32x4*)(gw + d * NEXP + 4);
    acc[0] += xv * g0[0]; acc[1] += xv * g0[1];
    acc[2] += xv * g0[2]; acc[3] += xv * g0[3];
    acc[4] += xv * g1[0]; acc[5] += xv * g1[1];
    acc[6] += xv * g1[2]; acc[7] += xv * g1[3];
  }
#pragma unroll
  for (int e = 0; e < NEXP; ++e) {
    float v = acc[e];
#pragma unroll
    for (int off = 32; off; off >>= 1) v += __shfl_xor(v, off);
    acc[e] = v;
  }
  if (lane == 0) {
    float m = acc[0]; int mi = 0;
#pragma unroll
    for (int e = 1; e < NEXP; ++e) if (acc[e] > m) { m = acc[e]; mi = e; }  // first-occurrence argmax
    float s = 0.f;
#pragma unroll
    for (int e = 0; e < NEXP; ++e) s += __expf(acc[e] - m);
    eidx[t] = mi;
    prob[t] = 1.f / s;       // softmax prob of the argmax expert
  }
}

// ---------------- deterministic per-expert cumsum positions + slot->token map + counts ----
__global__ void scan_kernel(const int* __restrict__ eidx, int* __restrict__ src,
                            int* __restrict__ counts) {
  __shared__ int buf[2][NEXP][256];
  const int tid = threadIdx.x;            // 256 threads, 1 block
  for (int i = tid; i < NEXP * CAPACITY; i += 256) src[i] = -1;
  const int t0 = tid * (TOKENS / 256);    // 32 tokens per thread
#pragma unroll
  for (int e = 0; e < NEXP; ++e) buf[0][e][tid] = 0;
  for (int k = 0; k < TOKENS / 256; ++k) {
    const int e = eidx[t0 + k];
    buf[0][e][tid]++;                     // LDS histogram
  }
  __syncthreads();
  int cur = 0;
  for (int off = 1; off < 256; off <<= 1) {   // Hillis-Steele inclusive scan over threads
#pragma unroll
    for (int e = 0; e < NEXP; ++e) {
      int v = buf[cur][e][tid];
      if (tid >= off) v += buf[cur][e][tid - off];
      buf[cur ^ 1][e][tid] = v;
    }
    __syncthreads();
    cur ^= 1;
  }
  if (tid < NEXP) counts[tid] = buf[cur][tid][255];   // per-expert totals (for M-tile skip)
  // exclusive base -> running counters in the other buffer (own slot only, no race)
#pragma unroll
  for (int e = 0; e < NEXP; ++e)
    buf[cur ^ 1][e][tid] = (tid > 0) ? buf[cur][e][tid - 1] : 0;
  for (int k = 0; k < TOKENS / 256; ++k) {
    const int t = t0 + k;
    const int e = eidx[t];
    const int p = buf[cur ^ 1][e][tid]++;
    if (p < CAPACITY) src[e * CAPACITY + p] = t;   // p>=CAP => token dropped
  }
}

// ---------------- dispatch: scatter tokens (f32 -> bf16) into [E*CAP, D]; zero empty slots
__global__ void dispatch_kernel(const float* __restrict__ tokens, const int* __restrict__ src,
                                __bf16* __restrict__ Xb) {
  const int slot = blockIdx.x;            // E*CAP blocks
  const int tid  = threadIdx.x;           // 256 threads, 4 elems each
  const int t = src[slot];
  bf16x4* dst = (bf16x4*)(Xb + (size_t)slot * DDIM);
  bf16x4 o;
  if (t >= 0) {
    const f32x4 v = ((const f32x4*)(tokens + (size_t)t * DDIM))[tid];
    o[0] = (__bf16)v[0]; o[1] = (__bf16)v[1]; o[2] = (__bf16)v[2]; o[3] = (__bf16)v[3];
  } else {
    o[0] = (__bf16)0.f; o[1] = (__bf16)0.f; o[2] = (__bf16)0.f; o[3] = (__bf16)0.f;
  }
  dst[tid] = o;
}

// ---------------- weight convert f32->bf16 with transpose: w[e][R][C] -> wt[e][C][R] ------
__global__ void transpose_convert_kernel(const float* __restrict__ w, __bf16* __restrict__ wt,
                                         int R, int C) {
  __shared__ __bf16 tile[64][66];         // pad 2: conflict-free transpose
  const int e = blockIdx.z;
  const float* wp = w + (size_t)e * R * C;
  __bf16* op = wt + (size_t)e * R * C;
  const int c0 = blockIdx.x * 64, r0 = blockIdx.y * 64;
  const int tid = threadIdx.x;            // 256 threads
#pragma unroll
  for (int p = 0; p < 4; ++p) {           // load 16 rows/pass, f32x4 per thread
    const int r = p * 16 + (tid >> 4);
    const int c = (tid & 15) * 4;
    const f32x4 v = *(const f32x4*)(wp + (size_t)(r0 + r) * C + c0 + c);
    tile[r][c]     = (__bf16)v[0]; tile[r][c + 1] = (__bf16)v[1];
    tile[r][c + 2] = (__bf16)v[2]; tile[r][c + 3] = (__bf16)v[3];
  }
  __syncthreads();
#pragma unroll
  for (int p = 0; p < 2; ++p) {           // store 32 out-rows/pass, bf16x8 per thread
    const int c  = p * 32 + (tid >> 3);
    const int rg = (tid & 7) * 8;
    bf16x8 o;
#pragma unroll
    for (int i = 0; i < 8; ++i) o[i] = tile[rg + i][c];
    *(bf16x8*)(op + (size_t)(c0 + c) * R + r0 + rg) = o;
  }
}

// ---------------- GEMM1: 128x128, BK=64, 4 waves, A in LDS + B DIRECT-FROM-GLOBAL ---------
// H[e] = relu(Xb[e][M,K] @ W1T[e][N,K]^T) -> bf16.
// LDS-BW diagnosis (R6/R14 invariant: ~2200cy per tile-iter regardless of concurrency):
// per block-iter the old form moved 96KB through LDS (fill 32 + read 64, each byte read
// by 2 waves) ~= 1100cy/block — the real bound. FIX: B-fragments read DIRECTLY from
// global (bf16x8 per lane; lanes gl=0..3 cover 64B-aligned rows of the L2-resident
// 256KB W1bT panel shared by the 10 same-tx blocks). LDS traffic 96->48KB; B's 32KB
// moves to the parallel L2 pipe. B loads have no LDS dependency -> issued before the
// A-barrier, pipelined across iters by the compiler. LDS 16KB + ~100 VGPR lifts the
// residency cap (launch_bounds 4 waves/EU).
__global__ __launch_bounds__(256, 4)
void gemm1_kernel(const __bf16* __restrict__ A, const __bf16* __restrict__ B,
                  __bf16* __restrict__ Cbf, const int* __restrict__ counts,
                  int K, size_t sA, size_t sB, size_t sC) {
  constexpr int N  = FDIM;
  constexpr int NX = N / 128;
  __shared__ __bf16 ldsA[128 * 64];       // A tile [128 m][64 k] = 16 KB only

  const int nwg = NX * NYT * NEXP;
  int wg = blockIdx.x;
  wg = (wg & 7) * (nwg >> 3) + (wg >> 3); // bijective XCD swizzle (nwg % 8 == 0)
  const int e   = wg / (NX * NYT);
  const int rem = wg - e * (NX * NYT);
  const int ty  = rem % NYT;              // y fastest: consecutive ids share B-panel (L2)
  const int tx  = rem / NYT;
  const int m0  = ty * 128, n0 = tx * 128;

  const int cnt   = counts[e];            // M-tile skip
  const int tiles = (cnt + 127) >> 7;
  if (ty >= ((tiles < NYT) ? tiles : NYT)) return;

  const __bf16* Ae = A + (size_t)e * sA;
  const __bf16* Be = B + (size_t)e * sB;
  const int tid = threadIdx.x;
  const int wid = tid >> 6, lane = tid & 63;
  const int wm = wid >> 1, wn = wid & 1;  // 2x2 wave grid, per-wave out 64x64
  const int rl = lane & 15, gl = lane >> 4;

  f32x4 acc[4][4];
#pragma unroll
  for (int m = 0; m < 4; ++m)
#pragma unroll
    for (int n = 0; n < 4; ++n) acc[m][n] = (f32x4){0.f, 0.f, 0.f, 0.f};

  // per-lane B base: row (n0 + wn*64 + n*16 + rl), k advances with kt/kk/gl
  const __bf16* Bl[4];
#pragma unroll
  for (int n = 0; n < 4; ++n)
    Bl[n] = Be + (size_t)(n0 + wn * 64 + n * 16 + rl) * K + gl * 8;

  for (int kt = 0; kt < K; kt += 64) {
    // B: direct global->VGPR, both phases (no LDS dependency; pipelines across iters)
    bf16x8 bv[2][4];
#pragma unroll
    for (int kk = 0; kk < 2; ++kk)
#pragma unroll
      for (int n = 0; n < 4; ++n)
        bv[kk][n] = *(const bf16x8*)(Bl[n] + kt + kk * 32);
    // A: async16 -> LDS, source pre-swizzled (m173 pattern, unchanged)
#pragma unroll
    for (int i = 0; i < 4; ++i) {
      const int s   = (wid * 4 + i) * 64 + lane;
      const int row = s >> 3;
      const int cg  = (s & 7) ^ (row & 7);
      async16(Ae + (size_t)(m0 + row) * K + kt + cg * 8, &ldsA[(wid * 4 + i) * 512]);
    }
    __syncthreads();                      // drains vmcnt before barrier
    const char* la = (const char*)&ldsA[0];
#pragma unroll
    for (int kk = 0; kk < 2; ++kk) {
      bf16x8 af[4];
#pragma unroll
      for (int m = 0; m < 4; ++m) {
        const int rowin = wm * 64 + m * 16 + rl;
        af[m] = *(const bf16x8*)(la + rowin * 128 + (((kk * 4 + gl) ^ (rowin & 7)) * 16));
      }
#pragma unroll
      for (int m = 0; m < 4; ++m)
#pragma unroll
        for (int n = 0; n < 4; ++n)
          acc[m][n] = __builtin_amdgcn_mfma_f32_16x16x32_bf16(af[m], bv[kk][n], acc[m][n], 0, 0, 0);
    }
    __syncthreads();
  }

  // C/D layout: col = lane&15, row = (lane>>4)*4 + reg  [m89/m91 verified]
  __bf16* Ce = Cbf + (size_t)e * sC;
#pragma unroll
  for (int m = 0; m < 4; ++m)
#pragma unroll
    for (int j = 0; j < 4; ++j) {
      const int row = m0 + wm * 64 + m * 16 + gl * 4 + j;
#pragma unroll
      for (int n = 0; n < 4; ++n) {
        const int col = n0 + wn * 64 + n * 16 + rl;
        float v = acc[m][n][j];
        v = v > 0.f ? v : 0.f;            // fused ReLU
        Ce[(size_t)row * N + col] = (__bf16)v;
      }
    }
}

// ---------------- GEMM2: 128x128, BK=64, 4 waves, fused f32-W transpose (R8, 146us) -------
// out[t] = prob[t] * (H[e] @ W2[e][K][N])[slot].  Measured-best form, frozen.
__global__ __launch_bounds__(256, 2)
void gemm2_kernel(const __bf16* __restrict__ A, const float* __restrict__ Bw,
                  float* __restrict__ out, const int* __restrict__ src,
                  const float* __restrict__ prob, const int* __restrict__ counts,
                  int K, size_t sA, size_t sBw) {
  constexpr int N  = DDIM;
  constexpr int NX = N / 128;
  __shared__ __bf16 lds[2][128 * 64];     // [0]=A tile [128 m][64 k], [1]=B tile [128 n][64 k]

  const int nwg = NX * NYT * NEXP;
  int wg = blockIdx.x;
  wg = (wg & 7) * (nwg >> 3) + (wg >> 3); // bijective XCD swizzle (nwg % 8 == 0)
  const int e   = wg / (NX * NYT);
  const int rem = wg - e * (NX * NYT);
  const int ty  = rem % NYT;
  const int tx  = rem / NYT;
  const int m0  = ty * 128, n0 = tx * 128;

  const int cnt   = counts[e];            // M-tile skip
  const int tiles = (cnt + 127) >> 7;
  if (ty >= ((tiles < NYT) ? tiles : NYT)) return;

  const __bf16* Ae = A + (size_t)e * sA;
  const float*  Be = Bw + (size_t)e * sBw;     // [K][N] f32
  const int tid = threadIdx.x;
  const int wid = tid >> 6, lane = tid & 63;
  const int wm = wid >> 1, wn = wid & 1;
  const int rl = lane & 15, gl = lane >> 4;
  const int nq = tid & 31;                // B staging: n-quad (cols 4nq..4nq+3)
  const int kb = tid >> 5;                // B staging: k-granule (rows 8kb..8kb+7)

  f32x4 acc[4][4];
#pragma unroll
  for (int m = 0; m < 4; ++m)
#pragma unroll
    for (int n = 0; n < 4; ++n) acc[m][n] = (f32x4){0.f, 0.f, 0.f, 0.f};

  for (int kt = 0; kt < K; kt += 64) {
    // B: coalesced f32 reads (rows k, consecutive n)
    f32x4 r[8];
#pragma unroll
    for (int i = 0; i < 8; ++i)
      r[i] = *(const f32x4*)(Be + (size_t)(kt + kb * 8 + i) * N + n0 + nq * 4);
    // A: async16, source pre-swizzled (m173 pattern)
#pragma unroll
    for (int i = 0; i < 4; ++i) {
      const int s   = (wid * 4 + i) * 64 + lane;
      const int row = s >> 3;
      const int cg  = (s & 7) ^ (row & 7);
      async16(Ae + (size_t)(m0 + row) * K + kt + cg * 8, &lds[0][(wid * 4 + i) * 512]);
    }
    // B: convert + transposed swizzled ds_write_b128
#pragma unroll
    for (int i2 = 0; i2 < 4; ++i2) {
      const int n  = nq * 4 + i2;
      const int sl = kb ^ (n & 7) ^ ((n >> 3) & 7);
      bf16x8 o;
#pragma unroll
      for (int i = 0; i < 8; ++i) o[i] = (__bf16)r[i][i2];
      *(bf16x8*)((char*)&lds[1][0] + n * 128 + sl * 16) = o;
    }
    __syncthreads();                      // drains vmcnt (async16) + lgkmcnt (ds_write)
    const char* la = (const char*)&lds[0][0];
    const char* lb = (const char*)&lds[1][0];
#pragma unroll
    for (int kk = 0; kk < 2; ++kk) {
      bf16x8 af[4], bv[4];
#pragma unroll
      for (int m = 0; m < 4; ++m) {
        const int rowin = wm * 64 + m * 16 + rl;
        af[m] = *(const bf16x8*)(la + rowin * 128 + (((kk * 4 + gl) ^ (rowin & 7)) * 16));
      }
#pragma unroll
      for (int n = 0; n < 4; ++n) {
        const int rowin = wn * 64 + n * 16 + rl;
        const int sl = (kk * 4 + gl) ^ (rowin & 7) ^ ((rowin >> 3) & 7);
        bv[n] = *(const bf16x8*)(lb + rowin * 128 + sl * 16);
      }
#pragma unroll
      for (int m = 0; m < 4; ++m)
#pragma unroll
        for (int n = 0; n < 4; ++n)
          acc[m][n] = __builtin_amdgcn_mfma_f32_16x16x32_bf16(af[m], bv[n], acc[m][n], 0, 0, 0);
    }
    __syncthreads();
  }

  // epilogue: fused combine (scale + scatter)
#pragma unroll
  for (int m = 0; m < 4; ++m)
#pragma unroll
    for (int j = 0; j < 4; ++j) {
      const int slot = m0 + wm * 64 + m * 16 + gl * 4 + j;
      const int t = src[e * CAPACITY + slot];
      if (t >= 0) {
        const float p = prob[t];
        float* op = out + (size_t)t * N;
#pragma unroll
        for (int n = 0; n < 4; ++n) {
          const int col = n0 + wn * 64 + n * 16 + rl;
          op[col] = p * acc[m][n][j];
        }
      }
    }
}

extern "C" void kernel_launch(void* const* d_in, const int* in_sizes, int n_in,
                              void* d_out, int out_size, void* d_ws, size_t ws_size,
                              hipStream_t stream) {
  const float* x  = (const float*)d_in[0];
  const float* gw = (const float*)d_in[1];
  const float* w1 = (const float*)d_in[2];
  const float* w2 = (const float*)d_in[3];
  float* out = (float*)d_out;

  char* ws = (char*)d_ws;
  size_t off = 0;
  auto alloc = [&](size_t bytes) {
    void* p = ws + off;
    off += (bytes + 255) & ~(size_t)255;
    return p;
  };
  __bf16* W1bT = (__bf16*)alloc((size_t)NEXP * FDIM * DDIM * 2);   // [E][F][D] bf16
  __bf16* Xb   = (__bf16*)alloc((size_t)NEXP * CAPACITY * DDIM * 2);
  __bf16* Hb   = (__bf16*)alloc((size_t)NEXP * CAPACITY * FDIM * 2);
  int*   eidx  = (int*)alloc(TOKENS * sizeof(int));
  float* prob  = (float*)alloc(TOKENS * sizeof(float));
  int*   srcm  = (int*)alloc(NEXP * CAPACITY * sizeof(int));
  int*   cnts  = (int*)alloc(NEXP * sizeof(int));
  (void)ws_size; (void)in_sizes; (void)n_in;

  hipMemsetAsync(d_out, 0, (size_t)out_size * sizeof(float), stream);  // dropped tokens -> 0

  gate_kernel<<<TOKENS, 64, 0, stream>>>(x, gw, eidx, prob);
  scan_kernel<<<1, 256, 0, stream>>>(eidx, srcm, cnts);
  dispatch_kernel<<<NEXP * CAPACITY, 256, 0, stream>>>(x, srcm, Xb);
  transpose_convert_kernel<<<dim3(FDIM / 64, DDIM / 64, NEXP), 256, 0, stream>>>(
      w1, W1bT, DDIM, FDIM);
  // H = relu(Xb @ W1^T): A-in-LDS + direct-global B, grid = 32*10*8 = 2560
  gemm1_kernel<<<(FDIM / 128) * NYT * NEXP, 256, 0, stream>>>(
      Xb, W1bT, Hb, cnts,
      DDIM, (size_t)CAPACITY * DDIM, (size_t)FDIM * DDIM, (size_t)CAPACITY * FDIM);
  // out[t] = prob[t] * (H @ W2)[slot]: f32 W2 direct, BK=64, grid = 8*10*8 = 640
  gemm2_kernel<<<(DDIM / 128) * NYT * NEXP, 256, 0, stream>>>(
      Hb, w2, out, srcm, prob, cnts,
      FDIM, (size_t)CAPACITY * FDIM, (size_t)FDIM * DDIM);
}

// Round 16
// 304.567 us; speedup vs baseline: 1.2755x; 1.2755x over previous
//
#include <hip/hip_runtime.h>
#include <hip/hip_bf16.h>

// Problem constants (B=4, S=2048, D=1024, E=8, F=4096)
#define TOKENS   8192
#define DDIM     1024
#define NEXP     8
#define FDIM     4096
#define CAPACITY 1280
#define NYT      10         // CAPACITY / 128 M-tiles

typedef __attribute__((ext_vector_type(8))) __bf16 bf16x8;
typedef __attribute__((ext_vector_type(4))) __bf16 bf16x4;
typedef __attribute__((ext_vector_type(4))) float  f32x4;

typedef __attribute__((address_space(1))) const void gvoid_t;
typedef __attribute__((address_space(3))) void       lvoid_t;

__device__ __forceinline__ void async16(const void* g, void* l) {
  // 16B per lane; LDS dest = wave-uniform base + lane*16 (HW behavior)
  __builtin_amdgcn_global_load_lds((gvoid_t*)g, (lvoid_t*)l, 16, 0, 0);
}

// ---------------- gating: logits, softmax, top-1 (all f32, must match ref routing) --------
__global__ void gate_kernel(const float* __restrict__ x, const float* __restrict__ gw,
                            int* __restrict__ eidx, float* __restrict__ prob) {
  const int t = blockIdx.x;
  const int lane = threadIdx.x;           // 64 threads
  const float* xp = x + (size_t)t * DDIM;
  float acc[NEXP];
#pragma unroll
  for (int e = 0; e < NEXP; ++e) acc[e] = 0.f;
#pragma unroll 4
  for (int i = 0; i < DDIM / 64; ++i) {
    const int d = i * 64 + lane;
    const float xv = xp[d];
    const f32x4 g0 = *(const f32x4*)(gw + d * NEXP);
    const f32x4 g1 = *(const f32x4*)(gw + d * NEXP + 4);
    acc[0] += xv * g0[0]; acc[1] += xv * g0[1];
    acc[2] += xv * g0[2]; acc[3] += xv * g0[3];
    acc[4] += xv * g1[0]; acc[5] += xv * g1[1];
    acc[6] += xv * g1[2]; acc[7] += xv * g1[3];
  }
#pragma unroll
  for (int e = 0; e < NEXP; ++e) {
    float v = acc[e];
#pragma unroll
    for (int off = 32; off; off >>= 1) v += __shfl_xor(v, off);
    acc[e] = v;
  }
  if (lane == 0) {
    float m = acc[0]; int mi = 0;
#pragma unroll
    for (int e = 1; e < NEXP; ++e) if (acc[e] > m) { m = acc[e]; mi = e; }  // first-occurrence argmax
    float s = 0.f;
#pragma unroll
    for (int e = 0; e < NEXP; ++e) s += __expf(acc[e] - m);
    eidx[t] = mi;
    prob[t] = 1.f / s;       // softmax prob of the argmax expert
  }
}

// ---------------- deterministic per-expert cumsum positions + slot->token map + counts ----
__global__ void scan_kernel(const int* __restrict__ eidx, int* __restrict__ src,
                            int* __restrict__ counts) {
  __shared__ int buf[2][NEXP][256];
  const int tid = threadIdx.x;            // 256 threads, 1 block
  for (int i = tid; i < NEXP * CAPACITY; i += 256) src[i] = -1;
  const int t0 = tid * (TOKENS / 256);    // 32 tokens per thread
#pragma unroll
  for (int e = 0; e < NEXP; ++e) buf[0][e][tid] = 0;
  for (int k = 0; k < TOKENS / 256; ++k) {
    const int e = eidx[t0 + k];
    buf[0][e][tid]++;                     // LDS histogram
  }
  __syncthreads();
  int cur = 0;
  for (int off = 1; off < 256; off <<= 1) {   // Hillis-Steele inclusive scan over threads
#pragma unroll
    for (int e = 0; e < NEXP; ++e) {
      int v = buf[cur][e][tid];
      if (tid >= off) v += buf[cur][e][tid - off];
      buf[cur ^ 1][e][tid] = v;
    }
    __syncthreads();
    cur ^= 1;
  }
  if (tid < NEXP) counts[tid] = buf[cur][tid][255];   // per-expert totals (for M-tile skip)
  // exclusive base -> running counters in the other buffer (own slot only, no race)
#pragma unroll
  for (int e = 0; e < NEXP; ++e)
    buf[cur ^ 1][e][tid] = (tid > 0) ? buf[cur][e][tid - 1] : 0;
  for (int k = 0; k < TOKENS / 256; ++k) {
    const int t = t0 + k;
    const int e = eidx[t];
    const int p = buf[cur ^ 1][e][tid]++;
    if (p < CAPACITY) src[e * CAPACITY + p] = t;   // p>=CAP => token dropped
  }
}

// ---------------- dispatch: scatter tokens (f32 -> bf16) into [E*CAP, D]; zero empty slots
__global__ void dispatch_kernel(const float* __restrict__ tokens, const int* __restrict__ src,
                                __bf16* __restrict__ Xb) {
  const int slot = blockIdx.x;            // E*CAP blocks
  const int tid  = threadIdx.x;           // 256 threads, 4 elems each
  const int t = src[slot];
  bf16x4* dst = (bf16x4*)(Xb + (size_t)slot * DDIM);
  bf16x4 o;
  if (t >= 0) {
    const f32x4 v = ((const f32x4*)(tokens + (size_t)t * DDIM))[tid];
    o[0] = (__bf16)v[0]; o[1] = (__bf16)v[1]; o[2] = (__bf16)v[2]; o[3] = (__bf16)v[3];
  } else {
    o[0] = (__bf16)0.f; o[1] = (__bf16)0.f; o[2] = (__bf16)0.f; o[3] = (__bf16)0.f;
  }
  dst[tid] = o;
}

// ---------------- weight convert f32->bf16 with transpose: w[e][R][C] -> wt[e][C][R] ------
// Vectorized both sides (G13): f32x4 global reads, bf16x8 global writes; 64x64 LDS tile.
// Runs at the ~5.8 TB/s BW floor (measured).
__global__ void transpose_convert_kernel(const float* __restrict__ w, __bf16* __restrict__ wt,
                                         int R, int C) {
  __shared__ __bf16 tile[64][66];         // pad 2: conflict-free transpose
  const int e = blockIdx.z;
  const float* wp = w + (size_t)e * R * C;
  __bf16* op = wt + (size_t)e * R * C;
  const int c0 = blockIdx.x * 64, r0 = blockIdx.y * 64;
  const int tid = threadIdx.x;            // 256 threads
#pragma unroll
  for (int p = 0; p < 4; ++p) {           // load 16 rows/pass, f32x4 per thread
    const int r = p * 16 + (tid >> 4);
    const int c = (tid & 15) * 4;
    const f32x4 v = *(const f32x4*)(wp + (size_t)(r0 + r) * C + c0 + c);
    tile[r][c]     = (__bf16)v[0]; tile[r][c + 1] = (__bf16)v[1];
    tile[r][c + 2] = (__bf16)v[2]; tile[r][c + 3] = (__bf16)v[3];
  }
  __syncthreads();
#pragma unroll
  for (int p = 0; p < 2; ++p) {           // store 32 out-rows/pass, bf16x8 per thread
    const int c  = p * 32 + (tid >> 3);
    const int rg = (tid & 7) * 8;
    bf16x8 o;
#pragma unroll
    for (int i = 0; i < 8; ++i) o[i] = tile[rg + i][c];
    *(bf16x8*)(op + (size_t)(c0 + c) * R + r0 + rg) = o;
  }
}

// ---------------- GEMM1: 128x128, BK=64, 4 waves, bf16 B^T via async16 (R8, 117us) --------
// H[e] = relu(Xb[e][M,K] @ W1T[e][N,K]^T) -> bf16.  MEASURED-BEST form, frozen.
// Falsification matrix (R9-R15): BK=128 (-), counted dbuf 64KB (0), counted dbuf 32KB/BK32
// (-), 256² 4-phase template (0), split tiles (-), direct-global B (-). This simple
// stage -> sync -> 2 phases -> sync loop with 32KB LDS is the family optimum.
__global__ __launch_bounds__(256, 2)
void gemm1_kernel(const __bf16* __restrict__ A, const __bf16* __restrict__ B,
                  __bf16* __restrict__ Cbf, const int* __restrict__ counts,
                  int K, size_t sA, size_t sB, size_t sC) {
  constexpr int N  = FDIM;
  constexpr int NX = N / 128;
  __shared__ __bf16 lds[2][128 * 64];     // [0]=A tile [128][64], [1]=B tile (32 KB total)

  const int nwg = NX * NYT * NEXP;
  int wg = blockIdx.x;
  wg = (wg & 7) * (nwg >> 3) + (wg >> 3); // bijective XCD swizzle (nwg % 8 == 0)
  const int e   = wg / (NX * NYT);
  const int rem = wg - e * (NX * NYT);
  const int ty  = rem % NYT;              // y fastest: consecutive ids share B-panel (L2)
  const int tx  = rem / NYT;
  const int m0  = ty * 128, n0 = tx * 128;

  const int cnt   = counts[e];            // M-tile skip
  const int tiles = (cnt + 127) >> 7;
  if (ty >= ((tiles < NYT) ? tiles : NYT)) return;

  const __bf16* Ae = A + (size_t)e * sA;
  const __bf16* Be = B + (size_t)e * sB;
  const int tid = threadIdx.x;
  const int wid = tid >> 6, lane = tid & 63;
  const int wm = wid >> 1, wn = wid & 1;  // 2x2 wave grid, per-wave out 64x64
  const int rl = lane & 15, gl = lane >> 4;

  f32x4 acc[4][4];
#pragma unroll
  for (int m = 0; m < 4; ++m)
#pragma unroll
    for (int n = 0; n < 4; ++n) acc[m][n] = (f32x4){0.f, 0.f, 0.f, 0.f};

  for (int kt = 0; kt < K; kt += 64) {
#pragma unroll
    for (int i = 0; i < 4; ++i) {         // stage 16KB A + 16KB B, source pre-swizzled
      const int s   = (wid * 4 + i) * 64 + lane;
      const int row = s >> 3;
      const int cg  = (s & 7) ^ (row & 7);
      async16(Ae + (size_t)(m0 + row) * K + kt + cg * 8, &lds[0][(wid * 4 + i) * 512]);
      async16(Be + (size_t)(n0 + row) * K + kt + cg * 8, &lds[1][(wid * 4 + i) * 512]);
    }
    __syncthreads();
    const char* la = (const char*)&lds[0][0];
    const char* lb = (const char*)&lds[1][0];
#pragma unroll
    for (int kk = 0; kk < 2; ++kk) {
      bf16x8 af[4], bv[4];
#pragma unroll
      for (int m = 0; m < 4; ++m) {
        const int rowin = wm * 64 + m * 16 + rl;
        af[m] = *(const bf16x8*)(la + rowin * 128 + (((kk * 4 + gl) ^ (rowin & 7)) * 16));
      }
#pragma unroll
      for (int n = 0; n < 4; ++n) {
        const int rowin = wn * 64 + n * 16 + rl;
        bv[n] = *(const bf16x8*)(lb + rowin * 128 + (((kk * 4 + gl) ^ (rowin & 7)) * 16));
      }
#pragma unroll
      for (int m = 0; m < 4; ++m)
#pragma unroll
        for (int n = 0; n < 4; ++n)
          acc[m][n] = __builtin_amdgcn_mfma_f32_16x16x32_bf16(af[m], bv[n], acc[m][n], 0, 0, 0);
    }
    __syncthreads();
  }

  // C/D layout: col = lane&15, row = (lane>>4)*4 + reg  [m89/m91 verified]
  __bf16* Ce = Cbf + (size_t)e * sC;
#pragma unroll
  for (int m = 0; m < 4; ++m)
#pragma unroll
    for (int j = 0; j < 4; ++j) {
      const int row = m0 + wm * 64 + m * 16 + gl * 4 + j;
#pragma unroll
      for (int n = 0; n < 4; ++n) {
        const int col = n0 + wn * 64 + n * 16 + rl;
        float v = acc[m][n][j];
        v = v > 0.f ? v : 0.f;            // fused ReLU
        Ce[(size_t)row * N + col] = (__bf16)v;
      }
    }
}

// ---------------- GEMM2: 128x128, BK=64, 4 waves, fused f32-W transpose (R8, 146us) -------
// out[t] = prob[t] * (H[e] @ W2[e][K][N])[slot].  MEASURED-BEST form, frozen.
// W2 f32 consumed directly (saves the 34.5us standalone transpose; K=4096 amortizes the
// staging — measured net win R7/R8); split-K (R14) and thin tiles (R13) both regressed.
__global__ __launch_bounds__(256, 2)
void gemm2_kernel(const __bf16* __restrict__ A, const float* __restrict__ Bw,
                  float* __restrict__ out, const int* __restrict__ src,
                  const float* __restrict__ prob, const int* __restrict__ counts,
                  int K, size_t sA, size_t sBw) {
  constexpr int N  = DDIM;
  constexpr int NX = N / 128;
  __shared__ __bf16 lds[2][128 * 64];     // [0]=A tile [128 m][64 k], [1]=B tile [128 n][64 k]

  const int nwg = NX * NYT * NEXP;
  int wg = blockIdx.x;
  wg = (wg & 7) * (nwg >> 3) + (wg >> 3); // bijective XCD swizzle (nwg % 8 == 0)
  const int e   = wg / (NX * NYT);
  const int rem = wg - e * (NX * NYT);
  const int ty  = rem % NYT;
  const int tx  = rem / NYT;
  const int m0  = ty * 128, n0 = tx * 128;

  const int cnt   = counts[e];            // M-tile skip
  const int tiles = (cnt + 127) >> 7;
  if (ty >= ((tiles < NYT) ? tiles : NYT)) return;

  const __bf16* Ae = A + (size_t)e * sA;
  const float*  Be = Bw + (size_t)e * sBw;     // [K][N] f32
  const int tid = threadIdx.x;
  const int wid = tid >> 6, lane = tid & 63;
  const int wm = wid >> 1, wn = wid & 1;
  const int rl = lane & 15, gl = lane >> 4;
  const int nq = tid & 31;                // B staging: n-quad (cols 4nq..4nq+3)
  const int kb = tid >> 5;                // B staging: k-granule (rows 8kb..8kb+7)

  f32x4 acc[4][4];
#pragma unroll
  for (int m = 0; m < 4; ++m)
#pragma unroll
    for (int n = 0; n < 4; ++n) acc[m][n] = (f32x4){0.f, 0.f, 0.f, 0.f};

  for (int kt = 0; kt < K; kt += 64) {
    // B: coalesced f32 reads (rows k, consecutive n)
    f32x4 r[8];
#pragma unroll
    for (int i = 0; i < 8; ++i)
      r[i] = *(const f32x4*)(Be + (size_t)(kt + kb * 8 + i) * N + n0 + nq * 4);
    // A: async16, source pre-swizzled (m173 pattern)
#pragma unroll
    for (int i = 0; i < 4; ++i) {
      const int s   = (wid * 4 + i) * 64 + lane;
      const int row = s >> 3;
      const int cg  = (s & 7) ^ (row & 7);
      async16(Ae + (size_t)(m0 + row) * K + kt + cg * 8, &lds[0][(wid * 4 + i) * 512]);
    }
    // B: convert + transposed swizzled ds_write_b128
#pragma unroll
    for (int i2 = 0; i2 < 4; ++i2) {
      const int n  = nq * 4 + i2;
      const int sl = kb ^ (n & 7) ^ ((n >> 3) & 7);
      bf16x8 o;
#pragma unroll
      for (int i = 0; i < 8; ++i) o[i] = (__bf16)r[i][i2];
      *(bf16x8*)((char*)&lds[1][0] + n * 128 + sl * 16) = o;
    }
    __syncthreads();                      // drains vmcnt (async16) + lgkmcnt (ds_write)
    const char* la = (const char*)&lds[0][0];
    const char* lb = (const char*)&lds[1][0];
#pragma unroll
    for (int kk = 0; kk < 2; ++kk) {
      bf16x8 af[4], bv[4];
#pragma unroll
      for (int m = 0; m < 4; ++m) {
        const int rowin = wm * 64 + m * 16 + rl;
        af[m] = *(const bf16x8*)(la + rowin * 128 + (((kk * 4 + gl) ^ (rowin & 7)) * 16));
      }
#pragma unroll
      for (int n = 0; n < 4; ++n) {
        const int rowin = wn * 64 + n * 16 + rl;
        const int sl = (kk * 4 + gl) ^ (rowin & 7) ^ ((rowin >> 3) & 7);
        bv[n] = *(const bf16x8*)(lb + rowin * 128 + sl * 16);
      }
#pragma unroll
      for (int m = 0; m < 4; ++m)
#pragma unroll
        for (int n = 0; n < 4; ++n)
          acc[m][n] = __builtin_amdgcn_mfma_f32_16x16x32_bf16(af[m], bv[n], acc[m][n], 0, 0, 0);
    }
    __syncthreads();
  }

  // epilogue: fused combine (scale + scatter)
#pragma unroll
  for (int m = 0; m < 4; ++m)
#pragma unroll
    for (int j = 0; j < 4; ++j) {
      const int slot = m0 + wm * 64 + m * 16 + gl * 4 + j;
      const int t = src[e * CAPACITY + slot];
      if (t >= 0) {
        const float p = prob[t];
        float* op = out + (size_t)t * N;
#pragma unroll
        for (int n = 0; n < 4; ++n) {
          const int col = n0 + wn * 64 + n * 16 + rl;
          op[col] = p * acc[m][n][j];
        }
      }
    }
}

extern "C" void kernel_launch(void* const* d_in, const int* in_sizes, int n_in,
                              void* d_out, int out_size, void* d_ws, size_t ws_size,
                              hipStream_t stream) {
  const float* x  = (const float*)d_in[0];
  const float* gw = (const float*)d_in[1];
  const float* w1 = (const float*)d_in[2];
  const float* w2 = (const float*)d_in[3];
  float* out = (float*)d_out;

  char* ws = (char*)d_ws;
  size_t off = 0;
  auto alloc = [&](size_t bytes) {
    void* p = ws + off;
    off += (bytes + 255) & ~(size_t)255;
    return p;
  };
  __bf16* W1bT = (__bf16*)alloc((size_t)NEXP * FDIM * DDIM * 2);   // [E][F][D] bf16
  __bf16* Xb   = (__bf16*)alloc((size_t)NEXP * CAPACITY * DDIM * 2);
  __bf16* Hb   = (__bf16*)alloc((size_t)NEXP * CAPACITY * FDIM * 2);
  int*   eidx  = (int*)alloc(TOKENS * sizeof(int));
  float* prob  = (float*)alloc(TOKENS * sizeof(float));
  int*   srcm  = (int*)alloc(NEXP * CAPACITY * sizeof(int));
  int*   cnts  = (int*)alloc(NEXP * sizeof(int));
  (void)ws_size; (void)in_sizes; (void)n_in;

  hipMemsetAsync(d_out, 0, (size_t)out_size * sizeof(float), stream);  // dropped tokens -> 0

  gate_kernel<<<TOKENS, 64, 0, stream>>>(x, gw, eidx, prob);
  scan_kernel<<<1, 256, 0, stream>>>(eidx, srcm, cnts);
  dispatch_kernel<<<NEXP * CAPACITY, 256, 0, stream>>>(x, srcm, Xb);
  transpose_convert_kernel<<<dim3(FDIM / 64, DDIM / 64, NEXP), 256, 0, stream>>>(
      w1, W1bT, DDIM, FDIM);
  // H = relu(Xb @ W1^T): bf16 B, BK=64, grid = 32*10*8 = 2560
  gemm1_kernel<<<(FDIM / 128) * NYT * NEXP, 256, 0, stream>>>(
      Xb, W1bT, Hb, cnts,
      DDIM, (size_t)CAPACITY * DDIM, (size_t)FDIM * DDIM, (size_t)CAPACITY * FDIM);
  // out[t] = prob[t] * (H @ W2)[slot]: f32 W2 direct, BK=64, grid = 8*10*8 = 640
  gemm2_kernel<<<(DDIM / 128) * NYT * NEXP, 256, 0, stream>>>(
      Hb, w2, out, srcm, prob, cnts,
      FDIM, (size_t)CAPACITY * FDIM, (size_t)FDIM * DDIM);
}

// Round 17
// 296.277 us; speedup vs baseline: 1.3111x; 1.0280x over previous
//
#include <hip/hip_runtime.h>
#include <hip/hip_bf16.h>

// Problem constants (B=4, S=2048, D=1024, E=8, F=4096)
#define TOKENS   8192
#define DDIM     1024
#define NEXP     8
#define FDIM     4096
#define CAPACITY 1280
#define NYT      10         // CAPACITY / 128 M-tiles
#define NWG1     ((FDIM / 128) * NYT * NEXP)   // 2560 gemm1 blocks
#define NWGT2    ((DDIM / 64) * (FDIM / 64) * NEXP)  // 16*64*8 = 8192 W2-transpose blocks

typedef __attribute__((ext_vector_type(8))) __bf16 bf16x8;
typedef __attribute__((ext_vector_type(4))) __bf16 bf16x4;
typedef __attribute__((ext_vector_type(4))) float  f32x4;

typedef __attribute__((address_space(1))) const void gvoid_t;
typedef __attribute__((address_space(3))) void       lvoid_t;

__device__ __forceinline__ void async16(const void* g, void* l) {
  // 16B per lane; LDS dest = wave-uniform base + lane*16 (HW behavior)
  __builtin_amdgcn_global_load_lds((gvoid_t*)g, (lvoid_t*)l, 16, 0, 0);
}

// ---------------- gating: logits, softmax, top-1 (all f32, must match ref routing) --------
__global__ void gate_kernel(const float* __restrict__ x, const float* __restrict__ gw,
                            int* __restrict__ eidx, float* __restrict__ prob) {
  const int t = blockIdx.x;
  const int lane = threadIdx.x;           // 64 threads
  const float* xp = x + (size_t)t * DDIM;
  float acc[NEXP];
#pragma unroll
  for (int e = 0; e < NEXP; ++e) acc[e] = 0.f;
#pragma unroll 4
  for (int i = 0; i < DDIM / 64; ++i) {
    const int d = i * 64 + lane;
    const float xv = xp[d];
    const f32x4 g0 = *(const f32x4*)(gw + d * NEXP);
    const f32x4 g1 = *(const f32x4*)(gw + d * NEXP + 4);
    acc[0] += xv * g0[0]; acc[1] += xv * g0[1];
    acc[2] += xv * g0[2]; acc[3] += xv * g0[3];
    acc[4] += xv * g1[0]; acc[5] += xv * g1[1];
    acc[6] += xv * g1[2]; acc[7] += xv * g1[3];
  }
#pragma unroll
  for (int e = 0; e < NEXP; ++e) {
    float v = acc[e];
#pragma unroll
    for (int off = 32; off; off >>= 1) v += __shfl_xor(v, off);
    acc[e] = v;
  }
  if (lane == 0) {
    float m = acc[0]; int mi = 0;
#pragma unroll
    for (int e = 1; e < NEXP; ++e) if (acc[e] > m) { m = acc[e]; mi = e; }  // first-occurrence argmax
    float s = 0.f;
#pragma unroll
    for (int e = 0; e < NEXP; ++e) s += __expf(acc[e] - m);
    eidx[t] = mi;
    prob[t] = 1.f / s;       // softmax prob of the argmax expert
  }
}

// ---------------- deterministic per-expert cumsum positions + slot->token map + counts ----
__global__ void scan_kernel(const int* __restrict__ eidx, int* __restrict__ src,
                            int* __restrict__ counts) {
  __shared__ int buf[2][NEXP][256];
  const int tid = threadIdx.x;            // 256 threads, 1 block
  for (int i = tid; i < NEXP * CAPACITY; i += 256) src[i] = -1;
  const int t0 = tid * (TOKENS / 256);    // 32 tokens per thread
#pragma unroll
  for (int e = 0; e < NEXP; ++e) buf[0][e][tid] = 0;
  for (int k = 0; k < TOKENS / 256; ++k) {
    const int e = eidx[t0 + k];
    buf[0][e][tid]++;                     // LDS histogram
  }
  __syncthreads();
  int cur = 0;
  for (int off = 1; off < 256; off <<= 1) {   // Hillis-Steele inclusive scan over threads
#pragma unroll
    for (int e = 0; e < NEXP; ++e) {
      int v = buf[cur][e][tid];
      if (tid >= off) v += buf[cur][e][tid - off];
      buf[cur ^ 1][e][tid] = v;
    }
    __syncthreads();
    cur ^= 1;
  }
  if (tid < NEXP) counts[tid] = buf[cur][tid][255];   // per-expert totals (for M-tile skip)
  // exclusive base -> running counters in the other buffer (own slot only, no race)
#pragma unroll
  for (int e = 0; e < NEXP; ++e)
    buf[cur ^ 1][e][tid] = (tid > 0) ? buf[cur][e][tid - 1] : 0;
  for (int k = 0; k < TOKENS / 256; ++k) {
    const int t = t0 + k;
    const int e = eidx[t];
    const int p = buf[cur ^ 1][e][tid]++;
    if (p < CAPACITY) src[e * CAPACITY + p] = t;   // p>=CAP => token dropped
  }
}

// ---------------- dispatch: scatter tokens (f32 -> bf16) into [E*CAP, D]; zero empty slots
__global__ void dispatch_kernel(const float* __restrict__ tokens, const int* __restrict__ src,
                                __bf16* __restrict__ Xb) {
  const int slot = blockIdx.x;            // E*CAP blocks
  const int tid  = threadIdx.x;           // 256 threads, 4 elems each
  const int t = src[slot];
  bf16x4* dst = (bf16x4*)(Xb + (size_t)slot * DDIM);
  bf16x4 o;
  if (t >= 0) {
    const f32x4 v = ((const f32x4*)(tokens + (size_t)t * DDIM))[tid];
    o[0] = (__bf16)v[0]; o[1] = (__bf16)v[1]; o[2] = (__bf16)v[2]; o[3] = (__bf16)v[3];
  } else {
    o[0] = (__bf16)0.f; o[1] = (__bf16)0.f; o[2] = (__bf16)0.f; o[3] = (__bf16)0.f;
  }
  dst[tid] = o;
}

// ---------------- weight convert f32->bf16 with transpose: w[e][R][C] -> wt[e][C][R] ------
// Standalone version (used for W1). f32x4 reads, bf16x8 writes; 64x64 LDS tile (~5.8 TB/s).
__global__ void transpose_convert_kernel(const float* __restrict__ w, __bf16* __restrict__ wt,
                                         int R, int C) {
  __shared__ __bf16 tile[64][66];         // pad 2: conflict-free transpose
  const int e = blockIdx.z;
  const float* wp = w + (size_t)e * R * C;
  __bf16* op = wt + (size_t)e * R * C;
  const int c0 = blockIdx.x * 64, r0 = blockIdx.y * 64;
  const int tid = threadIdx.x;            // 256 threads
#pragma unroll
  for (int p = 0; p < 4; ++p) {           // load 16 rows/pass, f32x4 per thread
    const int r = p * 16 + (tid >> 4);
    const int c = (tid & 15) * 4;
    const f32x4 v = *(const f32x4*)(wp + (size_t)(r0 + r) * C + c0 + c);
    tile[r][c]     = (__bf16)v[0]; tile[r][c + 1] = (__bf16)v[1];
    tile[r][c + 2] = (__bf16)v[2]; tile[r][c + 3] = (__bf16)v[3];
  }
  __syncthreads();
#pragma unroll
  for (int p = 0; p < 2; ++p) {           // store 32 out-rows/pass, bf16x8 per thread
    const int c  = p * 32 + (tid >> 3);
    const int rg = (tid & 7) * 8;
    bf16x8 o;
#pragma unroll
    for (int i = 0; i < 8; ++i) o[i] = tile[rg + i][c];
    *(bf16x8*)(op + (size_t)(c0 + c) * R + r0 + rg) = o;
  }
}

// ---------------- FUSED: gemm1 (blocks [0,NWG1)) + W2 transpose (blocks [NWG1, ...)) ------
// gemm1 is latency/LDS-bound (HBM 11%, 8 of 32 waves/CU); the W2 transpose is pure-HBM-BW
// (201 MB) with tiny LDS. Independent outputs (Hb vs W2bT) -> run concurrently in one
// launch via block-range split. Combined HBM demand ~2.6 TB/s << 6.3; LDS 2x32+3x32KB
// fits 160KB; 8+12 waves <= 32. Hides the 46us standalone W2 transpose under gemm1.
// gemm1 body = R8 measured-best form, byte-identical logic.
__global__ __launch_bounds__(256, 2)
void fused_g1w2t_kernel(const __bf16* __restrict__ A, const __bf16* __restrict__ B,
                        __bf16* __restrict__ Cbf, const int* __restrict__ counts,
                        const float* __restrict__ w2, __bf16* __restrict__ w2t) {
  __shared__ char smem[32768];            // gemm1: 2x16KB tiles; transpose: 8.4KB tile

  if (blockIdx.x < NWG1) {
    // ================= gemm1: 128x128, BK=64, 4 waves (R8 form) =================
    constexpr int N  = FDIM;
    constexpr int NX = N / 128;
    constexpr int K  = DDIM;
    __bf16* lds0 = (__bf16*)smem;           // A tile [128][64]
    __bf16* lds1 = (__bf16*)(smem + 16384); // B tile [128][64]

    const int nwg = NX * NYT * NEXP;        // 2560
    int wg = blockIdx.x;
    wg = (wg & 7) * (nwg >> 3) + (wg >> 3); // bijective XCD swizzle (nwg % 8 == 0)
    const int e   = wg / (NX * NYT);
    const int rem = wg - e * (NX * NYT);
    const int ty  = rem % NYT;              // y fastest: consecutive ids share B-panel (L2)
    const int tx  = rem / NYT;
    const int m0  = ty * 128, n0 = tx * 128;

    const int cnt   = counts[e];            // M-tile skip
    const int tiles = (cnt + 127) >> 7;
    if (ty >= ((tiles < NYT) ? tiles : NYT)) return;

    const __bf16* Ae = A + (size_t)e * ((size_t)CAPACITY * DDIM);
    const __bf16* Be = B + (size_t)e * ((size_t)FDIM * DDIM);
    const int tid = threadIdx.x;
    const int wid = tid >> 6, lane = tid & 63;
    const int wm = wid >> 1, wn = wid & 1;  // 2x2 wave grid, per-wave out 64x64
    const int rl = lane & 15, gl = lane >> 4;

    f32x4 acc[4][4];
#pragma unroll
    for (int m = 0; m < 4; ++m)
#pragma unroll
      for (int n = 0; n < 4; ++n) acc[m][n] = (f32x4){0.f, 0.f, 0.f, 0.f};

    for (int kt = 0; kt < K; kt += 64) {
#pragma unroll
      for (int i = 0; i < 4; ++i) {         // stage 16KB A + 16KB B, source pre-swizzled
        const int s   = (wid * 4 + i) * 64 + lane;
        const int row = s >> 3;
        const int cg  = (s & 7) ^ (row & 7);
        async16(Ae + (size_t)(m0 + row) * K + kt + cg * 8, &lds0[(wid * 4 + i) * 512]);
        async16(Be + (size_t)(n0 + row) * K + kt + cg * 8, &lds1[(wid * 4 + i) * 512]);
      }
      __syncthreads();
      const char* la = (const char*)lds0;
      const char* lb = (const char*)lds1;
#pragma unroll
      for (int kk = 0; kk < 2; ++kk) {
        bf16x8 af[4], bv[4];
#pragma unroll
        for (int m = 0; m < 4; ++m) {
          const int rowin = wm * 64 + m * 16 + rl;
          af[m] = *(const bf16x8*)(la + rowin * 128 + (((kk * 4 + gl) ^ (rowin & 7)) * 16));
        }
#pragma unroll
        for (int n = 0; n < 4; ++n) {
          const int rowin = wn * 64 + n * 16 + rl;
          bv[n] = *(const bf16x8*)(lb + rowin * 128 + (((kk * 4 + gl) ^ (rowin & 7)) * 16));
        }
#pragma unroll
        for (int m = 0; m < 4; ++m)
#pragma unroll
          for (int n = 0; n < 4; ++n)
            acc[m][n] = __builtin_amdgcn_mfma_f32_16x16x32_bf16(af[m], bv[n], acc[m][n], 0, 0, 0);
      }
      __syncthreads();
    }

    // C/D layout: col = lane&15, row = (lane>>4)*4 + reg  [m89/m91 verified]
    __bf16* Ce = Cbf + (size_t)e * ((size_t)CAPACITY * FDIM);
#pragma unroll
    for (int m = 0; m < 4; ++m)
#pragma unroll
      for (int j = 0; j < 4; ++j) {
        const int row = m0 + wm * 64 + m * 16 + gl * 4 + j;
#pragma unroll
        for (int n = 0; n < 4; ++n) {
          const int col = n0 + wn * 64 + n * 16 + rl;
          float v = acc[m][n][j];
          v = v > 0.f ? v : 0.f;            // fused ReLU
          Ce[(size_t)row * N + col] = (__bf16)v;
        }
      }
  } else {
    // ================= W2 transpose: w2[e][F][D] -> w2t[e][D][F] =================
    constexpr int R = FDIM, C = DDIM;
    const int idx = blockIdx.x - NWG1;      // 0 .. 8191
    const int e   = idx >> 10;              // / (16*64)
    const int rem = idx & 1023;
    const int by  = rem >> 4;               // 0..63 over R/64
    const int bx  = rem & 15;               // 0..15 over C/64
    auto tile = [&](int r, int c) -> __bf16& {
      return *(__bf16*)(smem + ((r * 66 + c) << 1));
    };
    const float* wp = w2 + (size_t)e * R * C;
    __bf16* op = w2t + (size_t)e * R * C;
    const int c0 = bx * 64, r0 = by * 64;
    const int tid = threadIdx.x;            // 256 threads
#pragma unroll
    for (int p = 0; p < 4; ++p) {           // load 16 rows/pass, f32x4 per thread
      const int r = p * 16 + (tid >> 4);
      const int c = (tid & 15) * 4;
      const f32x4 v = *(const f32x4*)(wp + (size_t)(r0 + r) * C + c0 + c);
      tile(r, c)     = (__bf16)v[0]; tile(r, c + 1) = (__bf16)v[1];
      tile(r, c + 2) = (__bf16)v[2]; tile(r, c + 3) = (__bf16)v[3];
    }
    __syncthreads();
#pragma unroll
    for (int p = 0; p < 2; ++p) {           // store 32 out-rows/pass, bf16x8 per thread
      const int c  = p * 32 + (tid >> 3);
      const int rg = (tid & 7) * 8;
      bf16x8 o;
#pragma unroll
      for (int i = 0; i < 8; ++i) o[i] = tile(rg + i, c);
      *(bf16x8*)(op + (size_t)(c0 + c) * R + r0 + rg) = o;
    }
  }
}

// ---------------- GEMM2: 128x128, BK=64, 4 waves, bf16 B^T via async16 (R6 form, 117us) ---
// out[t] = prob[t] * (H[e] @ W2bT[e][N,K]^T)[slot].  Pure-bf16 form — measured 117us in R6
// (vs 146us fused-f32); now affordable because the W2 transpose is hidden under gemm1.
__global__ __launch_bounds__(256, 2)
void gemm2_kernel(const __bf16* __restrict__ A, const __bf16* __restrict__ B,
                  float* __restrict__ out, const int* __restrict__ src,
                  const float* __restrict__ prob, const int* __restrict__ counts,
                  int K, size_t sA, size_t sB) {
  constexpr int N  = DDIM;
  constexpr int NX = N / 128;
  __shared__ __bf16 lds[2][128 * 64];     // [0]=A tile [128][64], [1]=B tile (32 KB total)

  const int nwg = NX * NYT * NEXP;
  int wg = blockIdx.x;
  wg = (wg & 7) * (nwg >> 3) + (wg >> 3); // bijective XCD swizzle (nwg % 8 == 0)
  const int e   = wg / (NX * NYT);
  const int rem = wg - e * (NX * NYT);
  const int ty  = rem % NYT;              // y fastest: consecutive ids share B-panel (L2)
  const int tx  = rem / NYT;
  const int m0  = ty * 128, n0 = tx * 128;

  const int cnt   = counts[e];            // M-tile skip
  const int tiles = (cnt + 127) >> 7;
  if (ty >= ((tiles < NYT) ? tiles : NYT)) return;

  const __bf16* Ae = A + (size_t)e * sA;
  const __bf16* Be = B + (size_t)e * sB;
  const int tid = threadIdx.x;
  const int wid = tid >> 6, lane = tid & 63;
  const int wm = wid >> 1, wn = wid & 1;  // 2x2 wave grid, per-wave out 64x64
  const int rl = lane & 15, gl = lane >> 4;

  f32x4 acc[4][4];
#pragma unroll
  for (int m = 0; m < 4; ++m)
#pragma unroll
    for (int n = 0; n < 4; ++n) acc[m][n] = (f32x4){0.f, 0.f, 0.f, 0.f};

  for (int kt = 0; kt < K; kt += 64) {
#pragma unroll
    for (int i = 0; i < 4; ++i) {         // stage 16KB A + 16KB B, source pre-swizzled
      const int s   = (wid * 4 + i) * 64 + lane;
      const int row = s >> 3;
      const int cg  = (s & 7) ^ (row & 7);
      async16(Ae + (size_t)(m0 + row) * K + kt + cg * 8, &lds[0][(wid * 4 + i) * 512]);
      async16(Be + (size_t)(n0 + row) * K + kt + cg * 8, &lds[1][(wid * 4 + i) * 512]);
    }
    __syncthreads();
    const char* la = (const char*)&lds[0][0];
    const char* lb = (const char*)&lds[1][0];
#pragma unroll
    for (int kk = 0; kk < 2; ++kk) {
      bf16x8 af[4], bv[4];
#pragma unroll
      for (int m = 0; m < 4; ++m) {
        const int rowin = wm * 64 + m * 16 + rl;
        af[m] = *(const bf16x8*)(la + rowin * 128 + (((kk * 4 + gl) ^ (rowin & 7)) * 16));
      }
#pragma unroll
      for (int n = 0; n < 4; ++n) {
        const int rowin = wn * 64 + n * 16 + rl;
        bv[n] = *(const bf16x8*)(lb + rowin * 128 + (((kk * 4 + gl) ^ (rowin & 7)) * 16));
      }
#pragma unroll
      for (int m = 0; m < 4; ++m)
#pragma unroll
        for (int n = 0; n < 4; ++n)
          acc[m][n] = __builtin_amdgcn_mfma_f32_16x16x32_bf16(af[m], bv[n], acc[m][n], 0, 0, 0);
    }
    __syncthreads();
  }

  // epilogue: fused combine (scale + scatter); C/D layout per m89/m91
#pragma unroll
  for (int m = 0; m < 4; ++m)
#pragma unroll
    for (int j = 0; j < 4; ++j) {
      const int slot = m0 + wm * 64 + m * 16 + gl * 4 + j;
      const int t = src[e * CAPACITY + slot];
      if (t >= 0) {
        const float p = prob[t];
        float* op = out + (size_t)t * N;
#pragma unroll
        for (int n = 0; n < 4; ++n) {
          const int col = n0 + wn * 64 + n * 16 + rl;
          op[col] = p * acc[m][n][j];
        }
      }
    }
}

extern "C" void kernel_launch(void* const* d_in, const int* in_sizes, int n_in,
                              void* d_out, int out_size, void* d_ws, size_t ws_size,
                              hipStream_t stream) {
  const float* x  = (const float*)d_in[0];
  const float* gw = (const float*)d_in[1];
  const float* w1 = (const float*)d_in[2];
  const float* w2 = (const float*)d_in[3];
  float* out = (float*)d_out;

  char* ws = (char*)d_ws;
  size_t off = 0;
  auto alloc = [&](size_t bytes) {
    void* p = ws + off;
    off += (bytes + 255) & ~(size_t)255;
    return p;
  };
  __bf16* W1bT = (__bf16*)alloc((size_t)NEXP * FDIM * DDIM * 2);   // [E][F][D] bf16
  __bf16* W2bT = (__bf16*)alloc((size_t)NEXP * DDIM * FDIM * 2);   // [E][D][F] bf16
  __bf16* Xb   = (__bf16*)alloc((size_t)NEXP * CAPACITY * DDIM * 2);
  __bf16* Hb   = (__bf16*)alloc((size_t)NEXP * CAPACITY * FDIM * 2);
  int*   eidx  = (int*)alloc(TOKENS * sizeof(int));
  float* prob  = (float*)alloc(TOKENS * sizeof(float));
  int*   srcm  = (int*)alloc(NEXP * CAPACITY * sizeof(int));
  int*   cnts  = (int*)alloc(NEXP * sizeof(int));
  (void)ws_size; (void)in_sizes; (void)n_in;

  hipMemsetAsync(d_out, 0, (size_t)out_size * sizeof(float), stream);  // dropped tokens -> 0

  gate_kernel<<<TOKENS, 64, 0, stream>>>(x, gw, eidx, prob);
  scan_kernel<<<1, 256, 0, stream>>>(eidx, srcm, cnts);
  dispatch_kernel<<<NEXP * CAPACITY, 256, 0, stream>>>(x, srcm, Xb);
  transpose_convert_kernel<<<dim3(FDIM / 64, DDIM / 64, NEXP), 256, 0, stream>>>(
      w1, W1bT, DDIM, FDIM);
  // gemm1 (H = relu(Xb @ W1^T)) CONCURRENT WITH W2 transpose: grid = 2560 + 8192
  fused_g1w2t_kernel<<<NWG1 + NWGT2, 256, 0, stream>>>(
      Xb, W1bT, Hb, cnts, w2, W2bT);
  // out[t] = prob[t] * (H @ W2bT^T)[slot]: pure-bf16 form, grid = 8*10*8 = 640
  gemm2_kernel<<<(DDIM / 128) * NYT * NEXP, 256, 0, stream>>>(
      Hb, W2bT, out, srcm, prob, cnts,
      FDIM, (size_t)CAPACITY * FDIM, (size_t)DDIM * FDIM);
}